// Round 1
// baseline (111.230 us; speedup 1.0000x reference)
//
#include <hip/hip_runtime.h>
#include <math.h>

#define BATCH 16
#define N_ROIS 1000
#define NUM_CLASSES 81
#define DET_MAX 100
#define MIN_CONF 0.7f
#define NMS_THRESH 0.3f

#define TILE 256   // ROIs staged per refine iteration (256*81*4 = 81 KB LDS)

// Single fused kernel: one block per batch image.
// Phase 1: tile-staged argmax + box refine + clip + direct LDS compaction
// Phase 2: rank-sort by (score desc, idx asc) + class-bucket scatter
// Phase 3: per-class greedy NMS (classes in parallel across threads)
// Phase 4: emit in global sorted order (== reference top_k order)
//
// The 81 KB probs tile is dead after phase 1, so it is aliased with the
// sort-phase arrays (24 KB) -> total LDS ~104 KB, 1 block/CU, 16 blocks.
__global__ __launch_bounds__(256) void detect_fused_v5(
    const float* __restrict__ rois, const float* __restrict__ probs,
    const float* __restrict__ deltas, const float* __restrict__ window,
    float* __restrict__ out)
{
    const int b = blockIdx.x;
    const int tid = threadIdx.x;

    // ---- phase-overlapped LDS region (82944 B) ----
    __shared__ __align__(16) char s_raw[TILE * NUM_CLASSES * 4];
    float* const s_probs = (float*)s_raw;                             // phase 1
    float (*const s_sbox)[4]    = (float(*)[4])s_raw;                 // 16000 B
    float* const s_ssc          = (float*)(s_raw + 16000);            //  4000 B
    unsigned char* const s_scls = (unsigned char*)(s_raw + 20000);    //  1000 B
    unsigned char* const s_kept = (unsigned char*)(s_raw + 21000);    //  1000 B
    short* const s_bucket       = (short*)(s_raw + 22000);            //  2000 B

    // ---- persistent LDS (candidates in compaction order) ----
    __shared__ __align__(16) float s_cbox[N_ROIS][4];   // 16000 B
    __shared__ float s_csc[N_ROIS];                     //  4000 B
    __shared__ short s_cidx[N_ROIS];                    //  2000 B
    __shared__ unsigned char s_ccls[N_ROIS];            //  1000 B
    __shared__ int s_cnt[NUM_CLASSES];
    __shared__ int s_off[NUM_CLASSES];
    __shared__ int s_C;

    if (tid == 0) s_C = 0;
    if (tid < NUM_CLASSES) s_cnt[tid] = 0;

    // zero this batch's output rows (d_out is poisoned before every replay)
    for (int i = tid; i < DET_MAX * 6; i += 256)
        out[(size_t)b * DET_MAX * 6 + i] = 0.0f;

    const float4 wv = ((const float4*)window)[b];   // broadcast load, cached
    __syncthreads();                                 // s_C / s_cnt init visible

    // ---------------- phase 1: refine + compact ----------------
    for (int t0 = 0; t0 < N_ROIS; t0 += TILE) {
        const int tn = (N_ROIS - t0 < TILE) ? (N_ROIS - t0) : TILE;  // 256,256,256,232

        // coalesced float4 staging; tn*81 divisible by 4 for all tiles,
        // base ((b*1000+t0)*81*4 B) is 16B-aligned since (b*1000+t0)%4==0
        const float4* src = (const float4*)(probs + ((size_t)b * N_ROIS + t0) * NUM_CLASSES);
        const int n4 = tn * NUM_CLASSES / 4;
        for (int i = tid; i < n4; i += 256)
            ((float4*)s_probs)[i] = src[i];
        __syncthreads();

        if (tid < tn) {
            const int r = t0 + tid;                    // roi index within batch
            // 4-chain argmax over 81 probs; lowest-index maximum (== jnp.argmax)
            const float* p = s_probs + tid * NUM_CLASSES;
            float bs0 = p[0], bs1 = p[1], bs2 = p[2], bs3 = p[3];
            int ib0 = 0, ib1 = 1, ib2 = 2, ib3 = 3;
            #pragma unroll
            for (int c = 4; c <= 76; c += 4) {
                float v0 = p[c], v1 = p[c + 1], v2 = p[c + 2], v3 = p[c + 3];
                if (v0 > bs0) { bs0 = v0; ib0 = c; }
                if (v1 > bs1) { bs1 = v1; ib1 = c + 1; }
                if (v2 > bs2) { bs2 = v2; ib2 = c + 2; }
                if (v3 > bs3) { bs3 = v3; ib3 = c + 3; }
            }
            { float v = p[80]; if (v > bs0) { bs0 = v; ib0 = 80; } }
            if (bs1 > bs0 || (bs1 == bs0 && ib1 < ib0)) { bs0 = bs1; ib0 = ib1; }
            if (bs3 > bs2 || (bs3 == bs2 && ib3 < ib2)) { bs2 = bs3; ib2 = ib3; }
            if (bs2 > bs0 || (bs2 == bs0 && ib2 < ib0)) { bs0 = bs2; ib0 = ib2; }
            const float bs = bs0;
            const int best = ib0;

            if ((best > 0) && (bs >= MIN_CONF)) {
                const size_t gidx = (size_t)b * N_ROIS + r;
                const float4 dd = ((const float4*)deltas)[gidx * NUM_CLASSES + best];
                float dy = dd.x * 0.1f, dx = dd.y * 0.1f, dh = dd.z * 0.2f, dw = dd.w * 0.2f;

                const float4 rr = ((const float4*)rois)[gidx];
                float y1 = rr.x, x1 = rr.y, y2 = rr.z, x2 = rr.w;
                float h = y2 - y1, w = x2 - x1;
                float cy = y1 + 0.5f * h, cx = x1 + 0.5f * w;
                cy += dy * h;
                cx += dx * w;
                h *= expf(dh);
                w *= expf(dw);
                float ny1 = cy - 0.5f * h;
                float nx1 = cx - 0.5f * w;
                float ny2 = ny1 + h;   // matches reference: y2 = y1 + h
                float nx2 = nx1 + w;

                ny1 = fminf(fmaxf(ny1, wv.x), wv.z);
                nx1 = fminf(fmaxf(nx1, wv.y), wv.w);
                ny2 = fminf(fmaxf(ny2, wv.x), wv.z);
                nx2 = fminf(fmaxf(nx2, wv.y), wv.w);

                const int k = atomicAdd(&s_C, 1);
                s_csc[k] = bs;
                s_cidx[k] = (short)r;
                s_ccls[k] = (unsigned char)best;
                atomicAdd(&s_cnt[best], 1);
                ((float4*)s_cbox)[k] = make_float4(ny1, nx1, ny2, nx2);
            }
        }
        __syncthreads();   // tile consumed before s_probs overwrite / aliasing
    }
    const int C = s_C;

    if (tid == 0) {        // class bucket offsets (81 trivial serial iters)
        int acc = 0;
        for (int c = 0; c < NUM_CLASSES; ++c) { s_off[c] = acc; acc += s_cnt[c]; }
    }
    __syncthreads();

    // ---- phase 2: rank-sort by (score desc, idx asc) + bucket scatter ----
    // (sc, idx) is a strict total order -> deterministic despite atomic
    // compaction order; crank = rank restricted to this candidate's class.
    for (int k = tid; k < C; k += 256) {
        float sk = s_csc[k];
        int ik = s_cidx[k];
        int ck = s_ccls[k];
        int rank = 0, crank = 0;
        for (int j = 0; j < C; ++j) {   // broadcast LDS reads
            float sj = s_csc[j];
            int before = (sj > sk) | ((sj == sk) & (s_cidx[j] < ik));
            rank += before;
            crank += before & (s_ccls[j] == ck);
        }
        s_ssc[rank] = sk;
        s_scls[rank] = (unsigned char)ck;
        ((float4*)s_sbox)[rank] = ((const float4*)s_cbox)[k];
        s_kept[rank] = 0;
        s_bucket[s_off[ck] + crank] = (short)rank;
    }
    __syncthreads();

    // ---- phase 3: per-class greedy NMS, all classes in parallel ----
    if (tid >= 1 && tid < NUM_CLASSES) {
        const int off = s_off[tid];
        const int m = s_cnt[tid];
        int kept_cnt = 0;
        for (int a = 0; a < m; ++a) {
            if (kept_cnt >= DET_MAX) break;
            int i = s_bucket[off + a];
            float4 bb = ((const float4*)s_sbox)[i];
            float area_b = (bb.z - bb.x) * (bb.w - bb.y);
            bool sup = false;
            for (int q = 0; q < a; ++q) {
                int j = s_bucket[off + q];
                if (!s_kept[j]) continue;
                float4 aa = ((const float4*)s_sbox)[j];
                float yy1 = fmaxf(aa.x, bb.x);
                float xx1 = fmaxf(aa.y, bb.y);
                float yy2 = fminf(aa.z, bb.z);
                float xx2 = fminf(aa.w, bb.w);
                float inter = fmaxf(yy2 - yy1, 0.0f) * fmaxf(xx2 - xx1, 0.0f);
                float area_a = (aa.z - aa.x) * (aa.w - aa.y);
                float uni = area_a + area_b - inter;
                if (inter / fmaxf(uni, 1e-10f) > NMS_THRESH) { sup = true; break; }
            }
            if (!sup) { s_kept[i] = 1; ++kept_cnt; }
        }
    }
    __syncthreads();

    // ---- phase 4: emit; slot = prefix count of kept (== top_k order) ----
    for (int i = tid; i < C; i += 256) {
        if (s_kept[i]) {
            int slot = 0;
            for (int j = 0; j < i; ++j) slot += s_kept[j];
            if (slot < DET_MAX) {
                float* o = out + (size_t)b * DET_MAX * 6 + slot * 6;
                float4 bb = ((const float4*)s_sbox)[i];
                o[0] = bb.x;
                o[1] = bb.y;
                o[2] = bb.z;
                o[3] = bb.w;
                o[4] = (float)s_scls[i];
                o[5] = s_ssc[i];
            }
        }
    }
}

extern "C" void kernel_launch(void* const* d_in, const int* in_sizes, int n_in,
                              void* d_out, int out_size, void* d_ws, size_t ws_size,
                              hipStream_t stream) {
    const float* rois      = (const float*)d_in[0];
    const float* fpn_class = (const float*)d_in[1];
    const float* fpn_bbox  = (const float*)d_in[2];
    const float* window    = (const float*)d_in[3];
    float* out = (float*)d_out;
    (void)d_ws; (void)ws_size;

    detect_fused_v5<<<BATCH, 256, 0, stream>>>(rois, fpn_class, fpn_bbox, window, out);
}